// Round 7
// baseline (34.280 us; speedup 1.0000x reference)
//
#include <hip/hip_runtime.h>
#include <math.h>

#define N_ROWS 4096
#define D_DIM  128
#define K_CLS  512
#define EPS    1e-6f
#define RPB    8                  // rows per block
#define NBLK   (N_ROWS / RPB)     // 512 blocks -> 2 blocks/CU, 4 waves/SIMD

typedef __attribute__((ext_vector_type(8))) short short8v;
typedef __attribute__((ext_vector_type(4))) float f32x4;

__device__ __forceinline__ unsigned short f2bf(float f) {
    unsigned int u = __float_as_uint(f);
    u += 0x7FFF + ((u >> 16) & 1);   // round-to-nearest-even
    return (unsigned short)(u >> 16);
}

// ---- prep: pack W (D,K) f32 -> bf16 B-fragments, c[k] = sum w^2 - 2*eps*sum w,
//      and zero the completion counter (no separate memset dispatch!). ----
// B-frag layout (mfma_f32_16x16x32_bf16): lane l holds col (l&15), k=(l>>4)*8+j.
// bpk[((t*32 + ctile)*64 + lane)*8 + j], t = k-step, ctile = col/16.
__global__ __launch_bounds__(256) void prep_kernel(
    const float* __restrict__ w,
    unsigned short* __restrict__ bpk,   // 4*32*64*8 bf16 = 128 KB
    float* __restrict__ c_arr,          // (K)
    unsigned int* __restrict__ cnt)
{
    const int b   = blockIdx.x;
    const int tid = threadIdx.x;
    if (b < 32) {
        const int gtid = b * 256 + tid;      // 0..8191
        const int lane = gtid & 63;
        const int c    = (gtid >> 6) & 31;
        const int t    = gtid >> 11;         // 0..3
        const int col  = c * 16 + (lane & 15);
        const int d0   = t * 32 + ((lane >> 4) << 3);
        unsigned short v[8];
#pragma unroll
        for (int j = 0; j < 8; ++j)
            v[j] = f2bf(w[(d0 + j) * K_CLS + col]);
        uint4 out;
        out.x = v[0] | ((unsigned)v[1] << 16);
        out.y = v[2] | ((unsigned)v[3] << 16);
        out.z = v[4] | ((unsigned)v[5] << 16);
        out.w = v[6] | ((unsigned)v[7] << 16);
        *(uint4*)&bpk[(size_t)gtid * 8] = out;
    } else {
        if (b == 32 && tid == 0) cnt[0] = 0;   // reset before main launches
        const int k = (b - 32) * 256 + tid;    // 0..511
        float s1 = 0.f, s2 = 0.f;
#pragma unroll 8
        for (int d = 0; d < D_DIM; ++d) {
            const float v = w[d * K_CLS + k];
            s1 += v;
            s2 = fmaf(v, v, s2);
        }
        c_arr[k] = s2 - 2.f * EPS * s1;
    }
}

// ---- main: block = 8 rows x 512 cols, 512 threads (8 waves). A-tile rows
// duplicated (tile row r holds real row r&7); expsum counts only q<2 lanes.
// Last-finished block reduces the loss mean (deterministic fixed-order sum).
__global__ __launch_bounds__(512) void proto_main_kernel(
    const float* __restrict__ x,
    const int*   __restrict__ label,
    const unsigned short* __restrict__ bpk,
    const float* __restrict__ c_arr,
    float* __restrict__ scores,
    float* __restrict__ loss_out,
    float* __restrict__ row_loss,
    unsigned int* __restrict__ cnt)
{
    const int tid  = threadIdx.x;
    const int wave = tid >> 6;
    const int lane = tid & 63;
    const int l15  = lane & 15;
    const int q    = lane >> 4;
    const int n0   = blockIdx.x * RPB;

    __shared__ float sxs[RPB];
    __shared__ float wm[8][16];
    __shared__ float we[8][16];
    __shared__ float gm[16];
    __shared__ float slab[RPB];
    __shared__ float red[8];
    __shared__ unsigned int isLast;

    // ---- sx[row] = sum_d (x+eps)^2 : one wave, 8 chunks of 16 d per row ----
    if (tid < 64) {
        const int row   = tid >> 3;
        const int chunk = tid & 7;
        const float* xr = &x[(size_t)(n0 + row) * D_DIM + chunk * 16];
        float p = 0.f;
#pragma unroll
        for (int i = 0; i < 4; ++i) {
            const float4 a = *(const float4*)&xr[i * 4];
            p = fmaf(a.x + EPS, a.x + EPS, p);
            p = fmaf(a.y + EPS, a.y + EPS, p);
            p = fmaf(a.z + EPS, a.z + EPS, p);
            p = fmaf(a.w + EPS, a.w + EPS, p);
        }
        p += __shfl_xor(p, 1);
        p += __shfl_xor(p, 2);
        p += __shfl_xor(p, 4);
        if (chunk == 0) sxs[row] = p;
    }

    // ---- A fragments: tile row (l&15) holds real row (l15&7) ----
    short8v afrag[4];
#pragma unroll
    for (int t = 0; t < 4; ++t) {
        const int row = n0 + (l15 & 7);
        const int d0  = t * 32 + q * 8;
        const float4 a = *(const float4*)&x[(size_t)row * D_DIM + d0];
        const float4 b = *(const float4*)&x[(size_t)row * D_DIM + d0 + 4];
        short8v f;
        f[0] = (short)f2bf(a.x); f[1] = (short)f2bf(a.y);
        f[2] = (short)f2bf(a.z); f[3] = (short)f2bf(a.w);
        f[4] = (short)f2bf(b.x); f[5] = (short)f2bf(b.y);
        f[6] = (short)f2bf(b.z); f[7] = (short)f2bf(b.w);
        afrag[t] = f;
    }

    // ---- B from packed bpk (coalesced dwordx4) + MFMA ----
    f32x4 acc[4];
    float ck[4];
    const int colbase = wave * 64;
#pragma unroll
    for (int c = 0; c < 4; ++c) {
        acc[c] = (f32x4){0.f, 0.f, 0.f, 0.f};
        const int ctile = wave * 4 + c;
        ck[c] = c_arr[ctile * 16 + l15];
#pragma unroll
        for (int t = 0; t < 4; ++t) {
            const short8v bf =
                *(const short8v*)&bpk[(((size_t)t * 32 + ctile) * 64 + lane) * 8];
            acc[c] = __builtin_amdgcn_mfma_f32_16x16x32_bf16(afrag[t], bf, acc[c], 0, 0, 0);
        }
    }

    __syncthreads();   // sxs ready

    // ---- scores (C/D: col = lane&15, tile row = q*4 + reg; rows >=8 are dups) ----
    float sv[4][4];
#pragma unroll
    for (int c = 0; c < 4; ++c) {
        const int col = colbase + c * 16 + l15;
#pragma unroll
        for (int j = 0; j < 4; ++j) {
            const int row16 = q * 4 + j;
            const float dist = sxs[row16 & 7] + ck[c] - 2.f * acc[c][j];
            sv[c][j] = -sqrtf(dist);
            if (row16 < RPB)
                scores[(size_t)(n0 + row16) * K_CLS + col] = sv[c][j];
        }
    }

    // ---- per-row max (dups harmless for max) ----
#pragma unroll
    for (int j = 0; j < 4; ++j) {
        float m = fmaxf(fmaxf(sv[0][j], sv[1][j]), fmaxf(sv[2][j], sv[3][j]));
        m = fmaxf(m, __shfl_xor(m, 1));
        m = fmaxf(m, __shfl_xor(m, 2));
        m = fmaxf(m, __shfl_xor(m, 4));
        m = fmaxf(m, __shfl_xor(m, 8));
        if (l15 == 0) wm[wave][q * 4 + j] = m;
    }
    __syncthreads();
    if (tid < 16) {
        float g = wm[0][tid];
#pragma unroll
        for (int ww = 1; ww < 8; ++ww) g = fmaxf(g, wm[ww][tid]);
        gm[tid] = g;
    }
    __syncthreads();

    // ---- expsum + label pick (q<2 half only feeds real rows 0..7) ----
#pragma unroll
    for (int j = 0; j < 4; ++j) {
        const int row16 = q * 4 + j;
        const float m = gm[row16];
        const int lab = label[n0 + (row16 & 7)];
        float e = 0.f;
#pragma unroll
        for (int c = 0; c < 4; ++c) {
            e += expf(sv[c][j] - m);
            if (row16 < RPB && (colbase + c * 16 + l15) == lab)
                slab[row16] = sv[c][j];
        }
        e += __shfl_xor(e, 1);
        e += __shfl_xor(e, 2);
        e += __shfl_xor(e, 4);
        e += __shfl_xor(e, 8);
        if (l15 == 0) we[wave][row16] = e;
    }
    __syncthreads();
    if (tid < RPB) {
        float es = we[0][tid];           // rows 0..7 only: no dup contributions
#pragma unroll
        for (int ww = 1; ww < 8; ++ww) es += we[ww][tid];
        row_loss[n0 + tid] = -(slab[tid] - gm[tid] - logf(es));
    }
    __syncthreads();

    // ---- last-block-done loss mean (no extra dispatch) ----
    if (tid == 0) {
        __threadfence();
        const unsigned int old = atomicAdd(cnt, 1u);
        isLast = (old == (unsigned)(NBLK - 1)) ? 1u : 0u;
    }
    __syncthreads();

    if (isLast) {
        __threadfence();
        float s = 0.f;
        for (int i = tid; i < N_ROWS; i += 512) s += row_loss[i];
        s += __shfl_xor(s, 1);
        s += __shfl_xor(s, 2);
        s += __shfl_xor(s, 4);
        s += __shfl_xor(s, 8);
        s += __shfl_xor(s, 16);
        s += __shfl_xor(s, 32);
        if (lane == 0) red[wave] = s;
        __syncthreads();
        if (tid == 0) {
            float tot = 0.f;
#pragma unroll
            for (int ww = 0; ww < 8; ++ww) tot += red[ww];
            loss_out[0] = tot * (1.0f / N_ROWS);
        }
    }
}

extern "C" void kernel_launch(void* const* d_in, const int* in_sizes, int n_in,
                              void* d_out, int out_size, void* d_ws, size_t ws_size,
                              hipStream_t stream)
{
    const float* x     = (const float*)d_in[0];
    const int*   label = (const int*)d_in[1];
    const float* w     = (const float*)d_in[2];

    float* scores   = (float*)d_out;                           // N*K floats
    float* loss_out = (float*)d_out + (size_t)N_ROWS * K_CLS;  // 1 float

    unsigned short* bpk = (unsigned short*)d_ws;               // 128 KB
    float* c_arr    = (float*)((char*)d_ws + 131072);          // 2 KB
    float* row_loss = (float*)((char*)d_ws + 133120);          // 16 KB
    unsigned int* cnt = (unsigned int*)((char*)d_ws + 149504); // 4 B

    prep_kernel<<<34, 256, 0, stream>>>(w, bpk, c_arr, cnt);
    proto_main_kernel<<<NBLK, 512, 0, stream>>>(x, label, bpk, c_arr,
                                                scores, loss_out, row_loss, cnt);
}

// Round 8
// 28.646 us; speedup vs baseline: 1.1967x; 1.1967x over previous
//
#include <hip/hip_runtime.h>
#include <hip/hip_bf16.h>
#include <math.h>

#define N_ROWS 4096
#define D_DIM  128
#define K_CLS  512
#define EPS    1e-6f
#define RPB    8                  // rows per block (A-tile rows duplicated in MFMA)
#define NBLK   (N_ROWS / RPB)     // 512 blocks -> 2 blocks/CU, 4 waves/SIMD

typedef __attribute__((ext_vector_type(8))) short short8v;
typedef __attribute__((ext_vector_type(4))) float f32x4;

__device__ __forceinline__ short f2bf_rne(float v) {
    return (short)__bfloat16_as_ushort(__float2bfloat16(v));
}

// Fused main: block = 8 rows x 512 cols, 512 threads (8 waves).
// Wave w owns cols 64w..64w+63 (4 col-tiles). B-fragments loaded straight from
// global w (L2-hot) with on-the-fly bf16 convert; c[k] = sum w^2 reduced
// in-register via quarter-group shuffles (eps*sum_w term dropped: |2*eps*sum_w|
// ~ 2.5e-6 -> score delta ~1e-7, far below threshold). MFMA A-tile rows 8..15
// duplicate rows 0..7; expsum/label use only tile rows 0..7.
__global__ __launch_bounds__(512) void proto_main_kernel(
    const float* __restrict__ x,
    const int*   __restrict__ label,
    const float* __restrict__ w,
    float* __restrict__ scores,
    float* __restrict__ row_loss)
{
    const int tid  = threadIdx.x;
    const int wave = tid >> 6;
    const int lane = tid & 63;
    const int l15  = lane & 15;
    const int q    = lane >> 4;
    const int n0   = blockIdx.x * RPB;

    __shared__ float sxs[RPB];
    __shared__ float wm[8][16];
    __shared__ float we[8][16];
    __shared__ float gm[16];
    __shared__ float slab[RPB];

    // ---- sx[row] = sum_d (x+eps)^2 : one wave, 8 chunks of 16 d per row ----
    if (tid < 64) {
        const int row   = tid >> 3;
        const int chunk = tid & 7;
        const float* xr = &x[(size_t)(n0 + row) * D_DIM + chunk * 16];
        float p = 0.f;
#pragma unroll
        for (int i = 0; i < 4; ++i) {
            const float4 a = *(const float4*)&xr[i * 4];
            p = fmaf(a.x + EPS, a.x + EPS, p);
            p = fmaf(a.y + EPS, a.y + EPS, p);
            p = fmaf(a.z + EPS, a.z + EPS, p);
            p = fmaf(a.w + EPS, a.w + EPS, p);
        }
        p += __shfl_xor(p, 1);
        p += __shfl_xor(p, 2);
        p += __shfl_xor(p, 4);
        if (chunk == 0) sxs[row] = p;
    }

    // ---- A fragments: tile row (l&15) holds real row (l15&7), k = q*8 + j ----
    short8v afrag[4];
#pragma unroll
    for (int t = 0; t < 4; ++t) {
        const int row = n0 + (l15 & 7);
        const int d0  = t * 32 + q * 8;
        const float4 a = *(const float4*)&x[(size_t)row * D_DIM + d0];
        const float4 b = *(const float4*)&x[(size_t)row * D_DIM + d0 + 4];
        short8v f;
        f[0] = f2bf_rne(a.x); f[1] = f2bf_rne(a.y);
        f[2] = f2bf_rne(a.z); f[3] = f2bf_rne(a.w);
        f[4] = f2bf_rne(b.x); f[5] = f2bf_rne(b.y);
        f[6] = f2bf_rne(b.z); f[7] = f2bf_rne(b.w);
        afrag[t] = f;
    }

    // ---- B fragments direct from global + c[k]=sum w^2 in-register + MFMA ----
    f32x4 acc[4];
    float ck[4];
    const int colbase = wave * 64;
#pragma unroll
    for (int c = 0; c < 4; ++c) {
        acc[c] = (f32x4){0.f, 0.f, 0.f, 0.f};
        float s2 = 0.f;
        const int col = colbase + c * 16 + l15;
#pragma unroll
        for (int t = 0; t < 4; ++t) {
            short8v bf;
#pragma unroll
            for (int j = 0; j < 8; ++j) {
                const float v = w[(size_t)(t * 32 + q * 8 + j) * K_CLS + col];
                s2 = fmaf(v, v, s2);
                bf[j] = f2bf_rne(v);
            }
            acc[c] = __builtin_amdgcn_mfma_f32_16x16x32_bf16(afrag[t], bf, acc[c], 0, 0, 0);
        }
        // lanes l, l^16, l^32, l^48 hold the same col, disjoint d-ranges
        s2 += __shfl_xor(s2, 16);
        s2 += __shfl_xor(s2, 32);
        ck[c] = s2;
    }

    __syncthreads();   // sxs ready

    // ---- scores (C/D: col = lane&15, tile row = q*4 + reg; rows >=8 are dups) ----
    float sv[4][4];
#pragma unroll
    for (int c = 0; c < 4; ++c) {
        const int col = colbase + c * 16 + l15;
#pragma unroll
        for (int j = 0; j < 4; ++j) {
            const int row16 = q * 4 + j;
            const float dist = sxs[row16 & 7] + ck[c] - 2.f * acc[c][j];
            sv[c][j] = -sqrtf(dist);
            if (row16 < RPB)
                scores[(size_t)(n0 + row16) * K_CLS + col] = sv[c][j];
        }
    }

    // ---- per-row max (dup rows produce identical values; harmless) ----
#pragma unroll
    for (int j = 0; j < 4; ++j) {
        float m = fmaxf(fmaxf(sv[0][j], sv[1][j]), fmaxf(sv[2][j], sv[3][j]));
        m = fmaxf(m, __shfl_xor(m, 1));
        m = fmaxf(m, __shfl_xor(m, 2));
        m = fmaxf(m, __shfl_xor(m, 4));
        m = fmaxf(m, __shfl_xor(m, 8));
        if (l15 == 0) wm[wave][q * 4 + j] = m;
    }
    __syncthreads();
    if (tid < 16) {
        float g = wm[0][tid];
#pragma unroll
        for (int ww = 1; ww < 8; ++ww) g = fmaxf(g, wm[ww][tid]);
        gm[tid] = g;
    }
    __syncthreads();

    // ---- expsum + label pick; only tile rows 0..7 are consumed ----
#pragma unroll
    for (int j = 0; j < 4; ++j) {
        const int row16 = q * 4 + j;
        const float m = gm[row16];
        const int lab = label[n0 + (row16 & 7)];
        float e = 0.f;
#pragma unroll
        for (int c = 0; c < 4; ++c) {
            e += expf(sv[c][j] - m);
            if (row16 < RPB && (colbase + c * 16 + l15) == lab)
                slab[row16] = sv[c][j];
        }
        e += __shfl_xor(e, 1);
        e += __shfl_xor(e, 2);
        e += __shfl_xor(e, 4);
        e += __shfl_xor(e, 8);
        if (l15 == 0) we[wave][row16] = e;
    }
    __syncthreads();
    if (tid < RPB) {
        float es = we[0][tid];
#pragma unroll
        for (int ww = 1; ww < 8; ++ww) es += we[ww][tid];
        row_loss[n0 + tid] = -(slab[tid] - gm[tid] - logf(es));
    }
}

// Deterministic single-block reduction of per-row losses -> mean.
__global__ __launch_bounds__(256) void loss_reduce_kernel(
    const float* __restrict__ row_loss, float* __restrict__ out)
{
    __shared__ float red[4];
    const int tid = threadIdx.x;
    float sum = 0.f;
    for (int i = tid; i < N_ROWS; i += 256) sum += row_loss[i];
#pragma unroll
    for (int off = 32; off >= 1; off >>= 1) sum += __shfl_xor(sum, off);
    if ((tid & 63) == 0) red[tid >> 6] = sum;
    __syncthreads();
    if (tid == 0)
        out[0] = (red[0] + red[1] + red[2] + red[3]) * (1.0f / N_ROWS);
}

extern "C" void kernel_launch(void* const* d_in, const int* in_sizes, int n_in,
                              void* d_out, int out_size, void* d_ws, size_t ws_size,
                              hipStream_t stream)
{
    const float* x     = (const float*)d_in[0];
    const int*   label = (const int*)d_in[1];
    const float* w     = (const float*)d_in[2];

    float* scores   = (float*)d_out;                           // N*K floats
    float* loss_out = (float*)d_out + (size_t)N_ROWS * K_CLS;  // 1 float
    float* row_loss = (float*)d_ws;                            // 4096 floats

    proto_main_kernel<<<NBLK, 512, 0, stream>>>(x, label, w, scores, row_loss);
    loss_reduce_kernel<<<1, 256, 0, stream>>>(row_loss, loss_out);
}

// Round 9
// 22.576 us; speedup vs baseline: 1.5184x; 1.2689x over previous
//
#include <hip/hip_runtime.h>
#include <hip/hip_bf16.h>
#include <math.h>

#define N_ROWS 4096
#define D_DIM  128
#define K_CLS  512
#define EPS    1e-6f
#define RPB    16                 // rows per block
#define NBLK   (N_ROWS / RPB)     // 256 blocks, 1 per CU; 16 waves = 4/SIMD

typedef __attribute__((ext_vector_type(8))) short short8v;
typedef __attribute__((ext_vector_type(4))) float f32x4;

__device__ __forceinline__ short f2bf_rne(float v) {
    return (short)__bfloat16_as_ushort(__float2bfloat16(v));
}

// Fused main: block = 16 rows x 512 cols, 1024 threads (16 waves, 4/SIMD).
// Wave w owns cols 32w..32w+31 (2 col-tiles): per-thread w work halved vs the
// 512-thread variant while per-block w traffic is unchanged (w read once per
// block, L2-hot). B-fragments converted bf16 on the fly; c[k] = sum w^2 via
// quarter-group shuffles (eps*sum_w term dropped: score delta ~1e-7).
__global__ __launch_bounds__(1024) void proto_main_kernel(
    const float* __restrict__ x,
    const int*   __restrict__ label,
    const float* __restrict__ w,
    float* __restrict__ scores,
    float* __restrict__ row_loss)
{
    const int tid  = threadIdx.x;
    const int wave = tid >> 6;        // 0..15
    const int lane = tid & 63;
    const int l15  = lane & 15;
    const int q    = lane >> 4;
    const int n0   = blockIdx.x * RPB;

    __shared__ float sxs[RPB];
    __shared__ float wm[16][16];
    __shared__ float we[16][16];
    __shared__ float gm[16];
    __shared__ float slab[RPB];

    // ---- sx[row] = sum_d (x+eps)^2 : threads 0..255, 16 chunks of 8 d per row ----
    if (tid < 256) {
        const int row   = tid >> 4;
        const int chunk = tid & 15;
        const float4 a = *(const float4*)&x[(size_t)(n0 + row) * D_DIM + chunk * 8];
        const float4 b = *(const float4*)&x[(size_t)(n0 + row) * D_DIM + chunk * 8 + 4];
        float p = 0.f;
        p = fmaf(a.x + EPS, a.x + EPS, p);
        p = fmaf(a.y + EPS, a.y + EPS, p);
        p = fmaf(a.z + EPS, a.z + EPS, p);
        p = fmaf(a.w + EPS, a.w + EPS, p);
        p = fmaf(b.x + EPS, b.x + EPS, p);
        p = fmaf(b.y + EPS, b.y + EPS, p);
        p = fmaf(b.z + EPS, b.z + EPS, p);
        p = fmaf(b.w + EPS, b.w + EPS, p);
        p += __shfl_xor(p, 1);
        p += __shfl_xor(p, 2);
        p += __shfl_xor(p, 4);
        p += __shfl_xor(p, 8);
        if (chunk == 0) sxs[row] = p;
    }

    // ---- A fragments: lane l -> row (l&15), k = q*8 + j within each 32-step ----
    short8v afrag[4];
#pragma unroll
    for (int t = 0; t < 4; ++t) {
        const int row = n0 + l15;
        const int d0  = t * 32 + q * 8;
        const float4 a = *(const float4*)&x[(size_t)row * D_DIM + d0];
        const float4 b = *(const float4*)&x[(size_t)row * D_DIM + d0 + 4];
        short8v f;
        f[0] = f2bf_rne(a.x); f[1] = f2bf_rne(a.y);
        f[2] = f2bf_rne(a.z); f[3] = f2bf_rne(a.w);
        f[4] = f2bf_rne(b.x); f[5] = f2bf_rne(b.y);
        f[6] = f2bf_rne(b.z); f[7] = f2bf_rne(b.w);
        afrag[t] = f;
    }

    // ---- B fragments direct from global + c[k]=sum w^2 in-register + MFMA ----
    f32x4 acc[2];
    float ck[2];
    const int colbase = wave * 32;
#pragma unroll
    for (int c = 0; c < 2; ++c) {
        acc[c] = (f32x4){0.f, 0.f, 0.f, 0.f};
        float s2 = 0.f;
        const int col = colbase + c * 16 + l15;
#pragma unroll
        for (int t = 0; t < 4; ++t) {
            short8v bf;
#pragma unroll
            for (int j = 0; j < 8; ++j) {
                const float v = w[(size_t)(t * 32 + q * 8 + j) * K_CLS + col];
                s2 = fmaf(v, v, s2);
                bf[j] = f2bf_rne(v);
            }
            acc[c] = __builtin_amdgcn_mfma_f32_16x16x32_bf16(afrag[t], bf, acc[c], 0, 0, 0);
        }
        // lanes l, l^16, l^32, l^48 hold the same col, disjoint d-ranges
        s2 += __shfl_xor(s2, 16);
        s2 += __shfl_xor(s2, 32);
        ck[c] = s2;
    }

    __syncthreads();   // sxs ready

    // ---- scores (C/D: col = lane&15, row = q*4 + reg) ----
    float sv[2][4];
#pragma unroll
    for (int c = 0; c < 2; ++c) {
        const int col = colbase + c * 16 + l15;
#pragma unroll
        for (int j = 0; j < 4; ++j) {
            const int row = q * 4 + j;
            const float dist = sxs[row] + ck[c] - 2.f * acc[c][j];
            sv[c][j] = -sqrtf(dist);
            scores[(size_t)(n0 + row) * K_CLS + col] = sv[c][j];
        }
    }

    // ---- per-row max over this wave's 32 cols, then cross-wave ----
#pragma unroll
    for (int j = 0; j < 4; ++j) {
        float m = fmaxf(sv[0][j], sv[1][j]);
        m = fmaxf(m, __shfl_xor(m, 1));
        m = fmaxf(m, __shfl_xor(m, 2));
        m = fmaxf(m, __shfl_xor(m, 4));
        m = fmaxf(m, __shfl_xor(m, 8));
        if (l15 == 0) wm[wave][q * 4 + j] = m;
    }
    __syncthreads();
    if (tid < 16) {
        float g = wm[0][tid];
#pragma unroll
        for (int ww = 1; ww < 16; ++ww) g = fmaxf(g, wm[ww][tid]);
        gm[tid] = g;
    }
    __syncthreads();

    // ---- expsum + label pick ----
#pragma unroll
    for (int j = 0; j < 4; ++j) {
        const int row = q * 4 + j;
        const float m = gm[row];
        const int lab = label[n0 + row];
        float e = 0.f;
#pragma unroll
        for (int c = 0; c < 2; ++c) {
            e += expf(sv[c][j] - m);
            if ((colbase + c * 16 + l15) == lab) slab[row] = sv[c][j];
        }
        e += __shfl_xor(e, 1);
        e += __shfl_xor(e, 2);
        e += __shfl_xor(e, 4);
        e += __shfl_xor(e, 8);
        if (l15 == 0) we[wave][row] = e;
    }
    __syncthreads();
    if (tid < RPB) {
        float es = we[0][tid];
#pragma unroll
        for (int ww = 1; ww < 16; ++ww) es += we[ww][tid];
        row_loss[n0 + tid] = -(slab[tid] - gm[tid] - logf(es));
    }
}

// Deterministic single-block reduction of per-row losses -> mean.
__global__ __launch_bounds__(256) void loss_reduce_kernel(
    const float* __restrict__ row_loss, float* __restrict__ out)
{
    __shared__ float red[4];
    const int tid = threadIdx.x;
    float sum = 0.f;
    for (int i = tid; i < N_ROWS; i += 256) sum += row_loss[i];
#pragma unroll
    for (int off = 32; off >= 1; off >>= 1) sum += __shfl_xor(sum, off);
    if ((tid & 63) == 0) red[tid >> 6] = sum;
    __syncthreads();
    if (tid == 0)
        out[0] = (red[0] + red[1] + red[2] + red[3]) * (1.0f / N_ROWS);
}

extern "C" void kernel_launch(void* const* d_in, const int* in_sizes, int n_in,
                              void* d_out, int out_size, void* d_ws, size_t ws_size,
                              hipStream_t stream)
{
    const float* x     = (const float*)d_in[0];
    const int*   label = (const int*)d_in[1];
    const float* w     = (const float*)d_in[2];

    float* scores   = (float*)d_out;                           // N*K floats
    float* loss_out = (float*)d_out + (size_t)N_ROWS * K_CLS;  // 1 float
    float* row_loss = (float*)d_ws;                            // 4096 floats

    proto_main_kernel<<<NBLK, 1024, 0, stream>>>(x, label, w, scores, row_loss);
    loss_reduce_kernel<<<1, 256, 0, stream>>>(row_loss, loss_out);
}

// Round 10
// 21.804 us; speedup vs baseline: 1.5722x; 1.0354x over previous
//
#include <hip/hip_runtime.h>
#include <hip/hip_bf16.h>
#include <math.h>

#define N_ROWS 4096
#define D_DIM  128
#define K_CLS  512
#define RPB    16                 // rows per block
#define NBLK   (N_ROWS / RPB)     // 256 blocks, 1 per CU; 16 waves = 4/SIMD

typedef __attribute__((ext_vector_type(8))) short short8v;
typedef __attribute__((ext_vector_type(4))) float f32x4;

__device__ __forceinline__ short f2bf_rne(float v) {
    return (short)__bfloat16_as_ushort(__float2bfloat16(v));
}

// Fused main: block = 16 rows x 512 cols, 1024 threads (16 waves, 4/SIMD).
// Wave w owns cols 32w..32w+31 (2 col-tiles). sx (=sum x^2) is fused into the
// A-fragment loads (fp32 path) and redistributed with shuffles - no separate
// phase, no LDS for it. eps cross-terms dropped (|delta score| ~ 4e-6 vs the
// 0.28 threshold and 0.0625 bf16 noise): dist = sx[r] + sum w^2[k] - 2*dot.
__global__ __launch_bounds__(1024) void proto_main_kernel(
    const float* __restrict__ x,
    const int*   __restrict__ label,
    const float* __restrict__ w,
    float* __restrict__ scores,
    float* __restrict__ row_loss)
{
    const int tid  = threadIdx.x;
    const int wave = tid >> 6;        // 0..15
    const int lane = tid & 63;
    const int l15  = lane & 15;
    const int q    = lane >> 4;
    const int n0   = blockIdx.x * RPB;

    __shared__ float wm[16][16];
    __shared__ float we[16][16];
    __shared__ float gm[16];
    __shared__ float slab[RPB];

    // ---- A fragments + fused row-sum of x^2 (lane l covers row l15, 32 d's) ----
    short8v afrag[4];
    float p = 0.f;
#pragma unroll
    for (int t = 0; t < 4; ++t) {
        const int row = n0 + l15;
        const int d0  = t * 32 + q * 8;
        const float4 a = *(const float4*)&x[(size_t)row * D_DIM + d0];
        const float4 b = *(const float4*)&x[(size_t)row * D_DIM + d0 + 4];
        p = fmaf(a.x, a.x, p); p = fmaf(a.y, a.y, p);
        p = fmaf(a.z, a.z, p); p = fmaf(a.w, a.w, p);
        p = fmaf(b.x, b.x, p); p = fmaf(b.y, b.y, p);
        p = fmaf(b.z, b.z, p); p = fmaf(b.w, b.w, p);
        short8v f;
        f[0] = f2bf_rne(a.x); f[1] = f2bf_rne(a.y);
        f[2] = f2bf_rne(a.z); f[3] = f2bf_rne(a.w);
        f[4] = f2bf_rne(b.x); f[5] = f2bf_rne(b.y);
        f[6] = f2bf_rne(b.z); f[7] = f2bf_rne(b.w);
        afrag[t] = f;
    }
    // quarter-groups (same l15, different q) hold disjoint d-ranges of one row
    p += __shfl_xor(p, 16);
    p += __shfl_xor(p, 32);           // p = ||x_{n0+l15}||^2, full row, fp32-exact
    // redistribute: epilogue needs rows q*4+j; lane r (q=0) holds row r's sum
    float sxr[4];
#pragma unroll
    for (int j = 0; j < 4; ++j) sxr[j] = __shfl(p, q * 4 + j);

    // ---- B fragments direct from global + c[k]=sum w^2 in-register + MFMA ----
    f32x4 acc[2];
    float ck[2];
    const int colbase = wave * 32;
#pragma unroll
    for (int c = 0; c < 2; ++c) {
        acc[c] = (f32x4){0.f, 0.f, 0.f, 0.f};
        float s2 = 0.f;
        const int col = colbase + c * 16 + l15;
#pragma unroll
        for (int t = 0; t < 4; ++t) {
            short8v bf;
#pragma unroll
            for (int j = 0; j < 8; ++j) {
                const float v = w[(size_t)(t * 32 + q * 8 + j) * K_CLS + col];
                s2 = fmaf(v, v, s2);
                bf[j] = f2bf_rne(v);
            }
            acc[c] = __builtin_amdgcn_mfma_f32_16x16x32_bf16(afrag[t], bf, acc[c], 0, 0, 0);
        }
        // lanes l, l^16, l^32, l^48 hold the same col, disjoint d-ranges
        s2 += __shfl_xor(s2, 16);
        s2 += __shfl_xor(s2, 32);
        ck[c] = s2;
    }

    // ---- scores (C/D: col = lane&15, row = q*4 + reg) ----
    float sv[2][4];
#pragma unroll
    for (int c = 0; c < 2; ++c) {
        const int col = colbase + c * 16 + l15;
#pragma unroll
        for (int j = 0; j < 4; ++j) {
            const int row = q * 4 + j;
            const float dist = sxr[j] + ck[c] - 2.f * acc[c][j];
            sv[c][j] = -sqrtf(dist);
            scores[(size_t)(n0 + row) * K_CLS + col] = sv[c][j];
        }
    }

    // ---- per-row max over this wave's 32 cols, then cross-wave ----
#pragma unroll
    for (int j = 0; j < 4; ++j) {
        float m = fmaxf(sv[0][j], sv[1][j]);
        m = fmaxf(m, __shfl_xor(m, 1));
        m = fmaxf(m, __shfl_xor(m, 2));
        m = fmaxf(m, __shfl_xor(m, 4));
        m = fmaxf(m, __shfl_xor(m, 8));
        if (l15 == 0) wm[wave][q * 4 + j] = m;
    }
    __syncthreads();
    if (tid < 16) {
        float g = wm[0][tid];
#pragma unroll
        for (int ww = 1; ww < 16; ++ww) g = fmaxf(g, wm[ww][tid]);
        gm[tid] = g;
    }
    __syncthreads();

    // ---- expsum + label pick ----
#pragma unroll
    for (int j = 0; j < 4; ++j) {
        const int row = q * 4 + j;
        const float m = gm[row];
        const int lab = label[n0 + row];
        float e = 0.f;
#pragma unroll
        for (int c = 0; c < 2; ++c) {
            e += expf(sv[c][j] - m);
            if ((colbase + c * 16 + l15) == lab) slab[row] = sv[c][j];
        }
        e += __shfl_xor(e, 1);
        e += __shfl_xor(e, 2);
        e += __shfl_xor(e, 4);
        e += __shfl_xor(e, 8);
        if (l15 == 0) we[wave][row] = e;
    }
    __syncthreads();
    if (tid < RPB) {
        float es = we[0][tid];
#pragma unroll
        for (int ww = 1; ww < 16; ++ww) es += we[ww][tid];
        row_loss[n0 + tid] = -(slab[tid] - gm[tid] - logf(es));
    }
}

// Deterministic single-block reduction of per-row losses -> mean.
__global__ __launch_bounds__(256) void loss_reduce_kernel(
    const float* __restrict__ row_loss, float* __restrict__ out)
{
    __shared__ float red[4];
    const int tid = threadIdx.x;
    float sum = 0.f;
    for (int i = tid; i < N_ROWS; i += 256) sum += row_loss[i];
#pragma unroll
    for (int off = 32; off >= 1; off >>= 1) sum += __shfl_xor(sum, off);
    if ((tid & 63) == 0) red[tid >> 6] = sum;
    __syncthreads();
    if (tid == 0)
        out[0] = (red[0] + red[1] + red[2] + red[3]) * (1.0f / N_ROWS);
}

extern "C" void kernel_launch(void* const* d_in, const int* in_sizes, int n_in,
                              void* d_out, int out_size, void* d_ws, size_t ws_size,
                              hipStream_t stream)
{
    const float* x     = (const float*)d_in[0];
    const int*   label = (const int*)d_in[1];
    const float* w     = (const float*)d_in[2];

    float* scores   = (float*)d_out;                           // N*K floats
    float* loss_out = (float*)d_out + (size_t)N_ROWS * K_CLS;  // 1 float
    float* row_loss = (float*)d_ws;                            // 4096 floats

    proto_main_kernel<<<NBLK, 1024, 0, stream>>>(x, label, w, scores, row_loss);
    loss_reduce_kernel<<<1, 256, 0, stream>>>(row_loss, loss_out);
}